// Round 4
// baseline (33225.607 us; speedup 1.0000x reference)
//
#include <hip/hip_runtime.h>
#include <stdint.h>

#define STEPS 100
#define BATCH 512

// ---------------------------------------------------------------------------
// Threefry2x32 (JAX-exact, 20 rounds)
// ---------------------------------------------------------------------------
__device__ __forceinline__ uint32_t rotl32(uint32_t v, int r) {
  return (v << r) | (v >> (32 - r));
}

__device__ __forceinline__ void tf2x32(uint32_t k0, uint32_t k1,
                                       uint32_t x0, uint32_t x1,
                                       uint32_t& o0, uint32_t& o1) {
  uint32_t ks2 = k0 ^ k1 ^ 0x1BD11BDAu;
  x0 += k0; x1 += k1;
#define RND(r) { x0 += x1; x1 = rotl32(x1, (r)); x1 ^= x0; }
  RND(13) RND(15) RND(26) RND(6)
  x0 += k1;  x1 += ks2 + 1u;
  RND(17) RND(29) RND(16) RND(24)
  x0 += ks2; x1 += k0 + 2u;
  RND(13) RND(15) RND(26) RND(6)
  x0 += k0;  x1 += k1 + 3u;
  RND(17) RND(29) RND(16) RND(24)
  x0 += k1;  x1 += ks2 + 4u;
  RND(13) RND(15) RND(26) RND(6)
  x0 += ks2; x1 += k0 + 5u;
#undef RND
  o0 = x0; o1 = x1;
}

__global__ void keys_kernel(uint32_t* __restrict__ keybuf) {
  int i = threadIdx.x;
  if (i < STEPS) {
    uint32_t a, b;
    tf2x32(0u, 42u, 0u, (uint32_t)i, a, b);
    keybuf[2 * i]     = a;
    keybuf[2 * i + 1] = b;
  }
}

// ---------------------------------------------------------------------------
// Poisson spikes, batch-innermost: pois_t[p*512 + b]; JAX index j = b*784 + p
// ---------------------------------------------------------------------------
#define NIN 401408  // 512*784

__global__ void poisson_t(const float* __restrict__ x,
                          const uint32_t* __restrict__ keybuf,
                          int step, float* __restrict__ pois_t) {
  int t = blockIdx.x * blockDim.x + threadIdx.x;
  if (t >= NIN) return;
  int p = t >> 9;
  int b = t & 511;
  int j = b * 784 + p;
  uint32_t k0 = keybuf[2 * step], k1 = keybuf[2 * step + 1];
  uint32_t o0, o1;
  tf2x32(k0, k1, 0u, (uint32_t)j, o0, o1);
  uint32_t bits = o0 ^ o1;
  float r = __uint_as_float((bits >> 9) | 0x3F800000u) - 1.0f;
  float xv = x[j];
  float sgn = (xv > 0.f) ? 1.f : ((xv < 0.f) ? -1.f : 0.f);
  pois_t[t] = (fabsf(xv) * 0.5f > r) ? sgn : 0.f;
}

// ---------------------------------------------------------------------------
// Fused conv1 (1->20, 5x5, pad 2) + IF fire + 2x2 avgpool + IF fire.
// Block = (pool-quad q, 256-batch half); lane = batch. Bitwise-stable.
// ---------------------------------------------------------------------------
__global__ __launch_bounds__(256) void conv1_pool1_fused(
    const float* __restrict__ pois_t, const float* __restrict__ w1,
    float* __restrict__ m1, float* __restrict__ m1s,
    float* __restrict__ sp1) {
  int q = blockIdx.x >> 1;                 // 0..195
  int b = ((blockIdx.x & 1) << 8) + threadIdx.x;
  int qy = q / 14, qx = q % 14;

  float acc[4][20];
#pragma unroll
  for (int s = 0; s < 4; ++s)
#pragma unroll
    for (int oc = 0; oc < 20; ++oc) acc[s][oc] = 0.f;

#pragma unroll
  for (int s = 0; s < 4; ++s) {
    int y = 2 * qy + (s >> 1);
    int x = 2 * qx + (s & 1);
#pragma unroll
    for (int ky = 0; ky < 5; ++ky) {
      int iy = y + ky - 2;
      if (iy < 0 || iy >= 28) continue;    // block-uniform
#pragma unroll
      for (int kx = 0; kx < 5; ++kx) {
        int ix = x + kx - 2;
        if (ix < 0 || ix >= 28) continue;  // block-uniform
        float v = pois_t[(iy * 28 + ix) * 512 + b];
#pragma unroll
        for (int oc = 0; oc < 20; ++oc)
          acc[s][oc] += w1[oc * 25 + ky * 5 + kx] * v;
      }
    }
  }

#pragma unroll
  for (int oc = 0; oc < 20; ++oc) {
    float s4[4];
#pragma unroll
    for (int s = 0; s < 4; ++s) {
      int y = 2 * qy + (s >> 1);
      int x = 2 * qx + (s & 1);
      int idx = (oc * 784 + y * 28 + x) * 512 + b;
      float m = m1[idx] + acc[s][oc];
      float sp = 0.f;
      if (m > 1.0f) { sp = 1.f; m = 0.f; }
      m1[idx] = m;
      s4[s] = sp;
    }
    float a = 0.25f * (((s4[0] + s4[1]) + s4[2]) + s4[3]);
    int pidx = (oc * 196 + q) * 512 + b;
    float mm = m1s[pidx] + a;
    float spp = 0.f;
    if (mm > 0.75f) { spp = 1.f; mm = 0.f; }
    m1s[pidx] = mm;
    sp1[pidx] = spp;
  }
}

// ---------------------------------------------------------------------------
// 2x2 avgpool + IF fire, batch-innermost (layer 2).
// ---------------------------------------------------------------------------
__global__ void pool_fire_t(const float* __restrict__ sin,
                            float* __restrict__ ms, float* __restrict__ sout,
                            int n, int H, float th) {
  int t = blockIdx.x * blockDim.x + threadIdx.x;
  if (t >= n) return;
  int b = t & 511;
  int r = t >> 9;
  int Ho = H >> 1;
  int pp = Ho * Ho;
  int c = r / pp, q = r % pp;
  int yo = q / Ho, xo = q % Ho;
  int ibase = (c * H * H + 2 * yo * H + 2 * xo) * 512 + b;
  float a = 0.25f * (sin[ibase] + sin[ibase + 512] +
                     sin[ibase + H * 512] + sin[ibase + H * 512 + 512]);
  float m = ms[t] + a;
  float sp = 0.f;
  if (m > th) { sp = 1.f; m = 0.f; }
  ms[t] = m;
  sout[t] = sp;
}

// ---------------------------------------------------------------------------
// w2 transpose: wT[q*50 + oc] = w2[oc*500 + q]
// ---------------------------------------------------------------------------
__global__ void transpose_w2(const float* __restrict__ w2,
                             float* __restrict__ wT) {
  int i = blockIdx.x * blockDim.x + threadIdx.x;
  if (i >= 25000) return;
  int oc = i / 500, q = i % 500;
  wT[q * 50 + oc] = w2[i];
}

// ---------------------------------------------------------------------------
// wf0 transpose, padded: wf0T[k*256 + n] = (n<200) ? wf0[n*2450+k] : 0
// ---------------------------------------------------------------------------
__global__ void transpose_wf0(const float* __restrict__ wf0,
                              float* __restrict__ wf0T) {
  int i = blockIdx.x * blockDim.x + threadIdx.x;
  if (i >= 2450 * 256) return;
  int k = i >> 8, n = i & 255;
  wf0T[i] = (n < 200) ? wf0[n * 2450 + k] : 0.f;
}

// ---------------------------------------------------------------------------
// conv2 (20->50, 5x5, pad 2, 14x14) + IF fire. Lane = batch, acc[50] regs.
// Sum order (ic,ky,kx) ascending — bitwise identical.
// ---------------------------------------------------------------------------
__global__ __launch_bounds__(256) void conv2_fire_t(
    const float* __restrict__ sp1, const float* __restrict__ wT,
    float* __restrict__ m2, float* __restrict__ s2) {
  int p = blockIdx.x >> 1;
  int b = ((blockIdx.x & 1) << 8) + threadIdx.x;
  int y = p / 14, x = p % 14;
  float acc[50];
#pragma unroll
  for (int oc = 0; oc < 50; ++oc) acc[oc] = 0.f;
  for (int ic = 0; ic < 20; ++ic) {
#pragma unroll
    for (int ky = 0; ky < 5; ++ky) {
      int iy = y + ky - 2;
      if (iy < 0 || iy >= 14) continue;
#pragma unroll
      for (int kx = 0; kx < 5; ++kx) {
        int ix = x + kx - 2;
        if (ix < 0 || ix >= 14) continue;
        float v = sp1[(ic * 196 + iy * 14 + ix) * 512 + b];
        const float* wrow = wT + (ic * 25 + ky * 5 + kx) * 50;
#pragma unroll
        for (int oc = 0; oc < 50; ++oc)
          acc[oc] += wrow[oc] * v;
      }
    }
  }
#pragma unroll
  for (int oc = 0; oc < 50; ++oc) {
    int idx = (oc * 196 + p) * 512 + b;
    float m = m2[idx] + acc[oc];
    float sp = 0.f;
    if (m > 1.0f) { sp = 1.f; m = 0.f; }
    m2[idx] = m;
    s2[idx] = sp;
  }
}

// ---------------------------------------------------------------------------
// fc0 weight-stationary: lane = output neuron n, block = 4 batch samples.
// wf0T[k][n] is a coalesced vector load shared by ALL blocks (L2-resident);
// sp2[k*512+b] is a scalar broadcast. k ascending per (n,b) with the same
// `acc += w*v` fmac form — bitwise identical to previous rounds.
// mf0/Tf0 are [b][n] (coalesced epilogue).
// ---------------------------------------------------------------------------
__global__ __launch_bounds__(256) void fc0_fire_ws(
    const float* __restrict__ sp2, const float* __restrict__ wf0T,
    float* __restrict__ mf0, float* __restrict__ Tf0) {
  int n = threadIdx.x;            // 0..255, active if < 200
  int b0 = blockIdx.x * 4;        // 128 blocks -> b0 = 0..508
  float acc[4] = {0.f, 0.f, 0.f, 0.f};
  for (int k0 = 0; k0 < 2450; k0 += 10) {   // 2450 = 245*10
    float wv[10];
#pragma unroll
    for (int u = 0; u < 10; ++u)
      wv[u] = wf0T[(k0 + u) * 256 + n];
    float sv[10][4];
#pragma unroll
    for (int u = 0; u < 10; ++u)
#pragma unroll
      for (int i = 0; i < 4; ++i)
        sv[u][i] = sp2[(k0 + u) * 512 + b0 + i];
#pragma unroll
    for (int u = 0; u < 10; ++u)
#pragma unroll
      for (int i = 0; i < 4; ++i)
        acc[i] += wv[u] * sv[u][i];
  }
  if (n < 200) {
#pragma unroll
    for (int i = 0; i < 4; ++i) {
      int idx = (b0 + i) * 200 + n;
      float m = mf0[idx] + acc[i];
      float sp = 0.f;
      if (m > 1.0f) { sp = 1.f; m = 0.f; }
      mf0[idx] = m;
      Tf0[idx] += sp;
    }
  }
}

// ---------------------------------------------------------------------------
// final: out[b][i] = (Tf0[b][:] . wf1[i][:]) / 1 / 100   (j ascending)
// ---------------------------------------------------------------------------
__global__ void fc1_out_t(const float* __restrict__ Tf0,
                          const float* __restrict__ wf1,
                          float* __restrict__ out) {
  int idx = blockIdx.x * blockDim.x + threadIdx.x;
  if (idx >= BATCH * 10) return;
  int b = idx / 10, i = idx % 10;
  float a = 0.f;
  for (int j = 0; j < 200; ++j) a += Tf0[b * 200 + j] * wf1[i * 200 + j];
  out[idx] = (a / 1.0f) / 100.0f;
}

// ---------------------------------------------------------------------------
extern "C" void kernel_launch(void* const* d_in, const int* in_sizes, int n_in,
                              void* d_out, int out_size, void* d_ws, size_t ws_size,
                              hipStream_t stream) {
  (void)in_sizes; (void)n_in; (void)out_size; (void)ws_size;
  const float* x   = (const float*)d_in[0];
  const float* w1  = (const float*)d_in[1];
  const float* w2  = (const float*)d_in[2];
  const float* wf0 = (const float*)d_in[3];
  const float* wf1 = (const float*)d_in[4];
  float* out = (float*)d_out;
  float* ws  = (float*)d_ws;

  // state (zeroed once per launch)
  float* m1   = ws;                 // [20*784][512]  = 8,028,160
  float* m1s  = m1   + 8028160;     // [20*196][512]  = 2,007,040
  float* m2   = m1s  + 2007040;     // [50*196][512]  = 5,017,600
  float* m2s  = m2   + 5017600;     // [50*49][512]   = 1,254,400
  float* mf0  = m2s  + 1254400;     // [512][200]     =   102,400
  float* Tf0  = mf0  + 102400;      // [512][200]     =   102,400
  const size_t state_f = 8028160 + 2007040 + 5017600 + 1254400 + 102400 + 102400;
  // transients
  float* pois = Tf0  + 102400;      // [784][512]     =   401,408
  float* sp1  = pois + 401408;      // [20*196][512]  = 2,007,040
  float* s2   = sp1  + 2007040;     // [50*196][512]  = 5,017,600
  float* sp2  = s2   + 5017600;     // [50*49][512]   = 1,254,400
  float* wT   = sp2  + 1254400;     // [500][50]      =    25,000
  float* wf0T = wT   + 25000;       // [2450][256]    =   627,200
  uint32_t* keybuf = (uint32_t*)(wf0T + 627200);  // 200 u32

  hipMemsetAsync(ws, 0, state_f * sizeof(float), stream);

  keys_kernel<<<1, 128, 0, stream>>>(keybuf);
  transpose_w2<<<(25000 + 255) / 256, 256, 0, stream>>>(w2, wT);
  transpose_wf0<<<(2450 * 256 + 255) / 256, 256, 0, stream>>>(wf0, wf0T);

  for (int s = 0; s < STEPS; ++s) {
    poisson_t<<<(NIN + 255) / 256, 256, 0, stream>>>(x, keybuf, s, pois);
    conv1_pool1_fused<<<196 * 2, 256, 0, stream>>>(pois, w1, m1, m1s, sp1);
    conv2_fire_t<<<196 * 2, 256, 0, stream>>>(sp1, wT, m2, s2);
    pool_fire_t<<<(1254400 + 255) / 256, 256, 0, stream>>>(s2, m2s, sp2,
                                                           1254400, 14, 0.75f);
    fc0_fire_ws<<<128, 256, 0, stream>>>(sp2, wf0T, mf0, Tf0);
  }
  fc1_out_t<<<(BATCH * 10 + 255) / 256, 256, 0, stream>>>(Tf0, wf1, out);
}

// Round 5
// 30227.798 us; speedup vs baseline: 1.0992x; 1.0992x over previous
//
#include <hip/hip_runtime.h>
#include <stdint.h>

#define STEPS 100
#define BATCH 512

// ---------------------------------------------------------------------------
// Threefry2x32 (JAX-exact, 20 rounds)
// ---------------------------------------------------------------------------
__device__ __forceinline__ uint32_t rotl32(uint32_t v, int r) {
  return (v << r) | (v >> (32 - r));
}

__device__ __forceinline__ void tf2x32(uint32_t k0, uint32_t k1,
                                       uint32_t x0, uint32_t x1,
                                       uint32_t& o0, uint32_t& o1) {
  uint32_t ks2 = k0 ^ k1 ^ 0x1BD11BDAu;
  x0 += k0; x1 += k1;
#define RND(r) { x0 += x1; x1 = rotl32(x1, (r)); x1 ^= x0; }
  RND(13) RND(15) RND(26) RND(6)
  x0 += k1;  x1 += ks2 + 1u;
  RND(17) RND(29) RND(16) RND(24)
  x0 += ks2; x1 += k0 + 2u;
  RND(13) RND(15) RND(26) RND(6)
  x0 += k0;  x1 += k1 + 3u;
  RND(17) RND(29) RND(16) RND(24)
  x0 += k1;  x1 += ks2 + 4u;
  RND(13) RND(15) RND(26) RND(6)
  x0 += ks2; x1 += k0 + 5u;
#undef RND
  o0 = x0; o1 = x1;
}

__global__ void keys_kernel(uint32_t* __restrict__ keybuf) {
  int i = threadIdx.x;
  if (i < STEPS) {
    uint32_t a, b;
    tf2x32(0u, 42u, 0u, (uint32_t)i, a, b);
    keybuf[2 * i]     = a;
    keybuf[2 * i + 1] = b;
  }
}

// ---------------------------------------------------------------------------
// Poisson spikes -> int8 {-1,0,1}, batch-innermost: pois[p*512+b].
// JAX element index j = b*784 + p.
// ---------------------------------------------------------------------------
#define NIN 401408  // 512*784

__global__ void poisson_t(const float* __restrict__ x,
                          const uint32_t* __restrict__ keybuf,
                          int step, int8_t* __restrict__ pois) {
  int t = blockIdx.x * blockDim.x + threadIdx.x;
  if (t >= NIN) return;
  int p = t >> 9;
  int b = t & 511;
  int j = b * 784 + p;
  uint32_t k0 = keybuf[2 * step], k1 = keybuf[2 * step + 1];
  uint32_t o0, o1;
  tf2x32(k0, k1, 0u, (uint32_t)j, o0, o1);
  uint32_t bits = o0 ^ o1;
  float r = __uint_as_float((bits >> 9) | 0x3F800000u) - 1.0f;
  float xv = x[j];
  int8_t sgn = (xv > 0.f) ? (int8_t)1 : ((xv < 0.f) ? (int8_t)-1 : (int8_t)0);
  pois[t] = (fabsf(xv) * 0.5f > r) ? sgn : (int8_t)0;
}

// ---------------------------------------------------------------------------
// Fused conv1 (1->20, 5x5, pad 2) + IF fire + 2x2 avgpool + IF fire.
// Block = (pool-quad q, 256-batch half); lane = batch. int8 in, int8 out.
// All FMA operand VALUES identical to fp32 rounds -> bitwise identical.
// ---------------------------------------------------------------------------
__global__ __launch_bounds__(256) void conv1_pool1_fused(
    const int8_t* __restrict__ pois, const float* __restrict__ w1,
    float* __restrict__ m1, float* __restrict__ m1s,
    uint8_t* __restrict__ sp1) {
  int q = blockIdx.x >> 1;                 // 0..195
  int b = ((blockIdx.x & 1) << 8) + threadIdx.x;
  int qy = q / 14, qx = q % 14;

  float acc[4][20];
#pragma unroll
  for (int s = 0; s < 4; ++s)
#pragma unroll
    for (int oc = 0; oc < 20; ++oc) acc[s][oc] = 0.f;

#pragma unroll
  for (int s = 0; s < 4; ++s) {
    int y = 2 * qy + (s >> 1);
    int x = 2 * qx + (s & 1);
#pragma unroll
    for (int ky = 0; ky < 5; ++ky) {
      int iy = y + ky - 2;
      if (iy < 0 || iy >= 28) continue;    // block-uniform
#pragma unroll
      for (int kx = 0; kx < 5; ++kx) {
        int ix = x + kx - 2;
        if (ix < 0 || ix >= 28) continue;  // block-uniform
        float v = (float)pois[(iy * 28 + ix) * 512 + b];
#pragma unroll
        for (int oc = 0; oc < 20; ++oc)
          acc[s][oc] += w1[oc * 25 + ky * 5 + kx] * v;
      }
    }
  }

#pragma unroll
  for (int oc = 0; oc < 20; ++oc) {
    float s4[4];
#pragma unroll
    for (int s = 0; s < 4; ++s) {
      int y = 2 * qy + (s >> 1);
      int x = 2 * qx + (s & 1);
      int idx = (oc * 784 + y * 28 + x) * 512 + b;
      float m = m1[idx] + acc[s][oc];
      float sp = 0.f;
      if (m > 1.0f) { sp = 1.f; m = 0.f; }
      m1[idx] = m;
      s4[s] = sp;
    }
    float a = 0.25f * (((s4[0] + s4[1]) + s4[2]) + s4[3]);
    int pidx = (oc * 196 + q) * 512 + b;
    float mm = m1s[pidx] + a;
    uint8_t spp = 0;
    if (mm > 0.75f) { spp = 1; mm = 0.f; }
    m1s[pidx] = mm;
    sp1[pidx] = spp;
  }
}

// ---------------------------------------------------------------------------
// w2 transpose: wT[q*50 + oc] = w2[oc*500 + q]
// ---------------------------------------------------------------------------
__global__ void transpose_w2(const float* __restrict__ w2,
                             float* __restrict__ wT) {
  int i = blockIdx.x * blockDim.x + threadIdx.x;
  if (i >= 25000) return;
  int oc = i / 500, q = i % 500;
  wT[q * 50 + oc] = w2[i];
}

// ---------------------------------------------------------------------------
// conv2 (20->50, 5x5, pad 2, 14x14) + IF fire. Lane = batch, acc[50] regs.
// int8 input (L2-resident 2MB), uint8 spike output. Sum order (ic,ky,kx).
// ---------------------------------------------------------------------------
__global__ __launch_bounds__(256) void conv2_fire_t(
    const uint8_t* __restrict__ sp1, const float* __restrict__ wT,
    float* __restrict__ m2, uint8_t* __restrict__ s2) {
  int p = blockIdx.x >> 1;
  int b = ((blockIdx.x & 1) << 8) + threadIdx.x;
  int y = p / 14, x = p % 14;
  float acc[50];
#pragma unroll
  for (int oc = 0; oc < 50; ++oc) acc[oc] = 0.f;
  for (int ic = 0; ic < 20; ++ic) {
#pragma unroll
    for (int ky = 0; ky < 5; ++ky) {
      int iy = y + ky - 2;
      if (iy < 0 || iy >= 14) continue;
#pragma unroll
      for (int kx = 0; kx < 5; ++kx) {
        int ix = x + kx - 2;
        if (ix < 0 || ix >= 14) continue;
        float v = (float)sp1[(ic * 196 + iy * 14 + ix) * 512 + b];
        const float* wrow = wT + (ic * 25 + ky * 5 + kx) * 50;
#pragma unroll
        for (int oc = 0; oc < 50; ++oc)
          acc[oc] += wrow[oc] * v;
      }
    }
  }
#pragma unroll
  for (int oc = 0; oc < 50; ++oc) {
    int idx = (oc * 196 + p) * 512 + b;
    float m = m2[idx] + acc[oc];
    uint8_t sp = 0;
    if (m > 1.0f) { sp = 1; m = 0.f; }
    m2[idx] = m;
    s2[idx] = sp;
  }
}

// ---------------------------------------------------------------------------
// 2x2 avgpool + IF fire (layer 2), u8 in / u8 out, batch-innermost.
// ---------------------------------------------------------------------------
__global__ void pool_fire_t(const uint8_t* __restrict__ sin,
                            float* __restrict__ ms, uint8_t* __restrict__ sout,
                            int n, int H, float th) {
  int t = blockIdx.x * blockDim.x + threadIdx.x;
  if (t >= n) return;
  int b = t & 511;
  int r = t >> 9;
  int Ho = H >> 1;
  int pp = Ho * Ho;
  int c = r / pp, q = r % pp;
  int yo = q / Ho, xo = q % Ho;
  int ibase = (c * H * H + 2 * yo * H + 2 * xo) * 512 + b;
  float s00 = (float)sin[ibase];
  float s01 = (float)sin[ibase + 512];
  float s10 = (float)sin[ibase + H * 512];
  float s11 = (float)sin[ibase + H * 512 + 512];
  float a = 0.25f * (((s00 + s01) + s10) + s11);
  float m = ms[t] + a;
  uint8_t sp = 0;
  if (m > th) { sp = 1; m = 0.f; }
  ms[t] = m;
  sout[t] = sp;
}

// ---------------------------------------------------------------------------
// fc0 (2450->200) + IF fire + Tf0 accumulate. Lane = batch, 4 n per thread.
// sp2 u8 (1.25MB, L2-resident); 100 blocks; k ascending per (n,b) with the
// same fmac form -> bitwise identical. mf0/Tf0 are [n][b].
// ---------------------------------------------------------------------------
__global__ __launch_bounds__(256) void fc0_fire_t4(
    const uint8_t* __restrict__ sp2, const float* __restrict__ wf0,
    float* __restrict__ mf0, float* __restrict__ Tf0) {
  int g = blockIdx.x >> 1;                        // 0..49 n-group
  int b = ((blockIdx.x & 1) << 8) + threadIdx.x;  // 0..511
  int n0 = g * 4;
  const float* w0 = wf0 + n0 * 2450;
  float acc[4] = {0.f, 0.f, 0.f, 0.f};
  for (int k0 = 0; k0 < 2450; k0 += 10) {         // 2450 = 245*10
    float v[10];
#pragma unroll
    for (int u = 0; u < 10; ++u)
      v[u] = (float)sp2[(k0 + u) * 512 + b];
#pragma unroll
    for (int u = 0; u < 10; ++u)
#pragma unroll
      for (int i = 0; i < 4; ++i)
        acc[i] += w0[i * 2450 + k0 + u] * v[u];
  }
#pragma unroll
  for (int i = 0; i < 4; ++i) {
    int idx = (n0 + i) * 512 + b;
    float m = mf0[idx] + acc[i];
    float sp = 0.f;
    if (m > 1.0f) { sp = 1.f; m = 0.f; }
    mf0[idx] = m;
    Tf0[idx] += sp;
  }
}

// ---------------------------------------------------------------------------
// final: out[b][i] = (Tf0[.][b] . wf1[i][.]) / 1 / 100   (j ascending)
// ---------------------------------------------------------------------------
__global__ void fc1_out_t(const float* __restrict__ Tf0,
                          const float* __restrict__ wf1,
                          float* __restrict__ out) {
  int idx = blockIdx.x * blockDim.x + threadIdx.x;
  if (idx >= BATCH * 10) return;
  int b = idx / 10, i = idx % 10;
  float a = 0.f;
  for (int j = 0; j < 200; ++j) a += Tf0[j * 512 + b] * wf1[i * 200 + j];
  out[idx] = (a / 1.0f) / 100.0f;
}

// ---------------------------------------------------------------------------
extern "C" void kernel_launch(void* const* d_in, const int* in_sizes, int n_in,
                              void* d_out, int out_size, void* d_ws, size_t ws_size,
                              hipStream_t stream) {
  (void)in_sizes; (void)n_in; (void)out_size; (void)ws_size;
  const float* x   = (const float*)d_in[0];
  const float* w1  = (const float*)d_in[1];
  const float* w2  = (const float*)d_in[2];
  const float* wf0 = (const float*)d_in[3];
  const float* wf1 = (const float*)d_in[4];
  float* out = (float*)d_out;
  float* ws  = (float*)d_ws;

  // fp32 state (zeroed once per launch), batch-innermost
  float* m1   = ws;                 // [20*784][512]  = 8,028,160
  float* m1s  = m1   + 8028160;     // [20*196][512]  = 2,007,040
  float* m2   = m1s  + 2007040;     // [50*196][512]  = 5,017,600
  float* m2s  = m2   + 5017600;     // [50*49][512]   = 1,254,400
  float* mf0  = m2s  + 1254400;     // [200][512]     =   102,400
  float* Tf0  = mf0  + 102400;      // [200][512]     =   102,400
  const size_t state_f = 8028160 + 2007040 + 5017600 + 1254400 + 102400 + 102400;
  // fp32 transients
  float* wT   = Tf0  + 102400;      // [500][50]      =    25,000
  uint32_t* keybuf = (uint32_t*)(wT + 25000);       // 200 u32
  // int8 spike transients
  int8_t*  pois = (int8_t*)(keybuf + 256);          // [784][512]    =   401,408 B
  uint8_t* sp1  = (uint8_t*)(pois + 401408);        // [20*196][512] = 2,007,040 B
  uint8_t* s2   = sp1 + 2007040;                    // [50*196][512] = 5,017,600 B
  uint8_t* sp2  = s2  + 5017600;                    // [50*49][512]  = 1,254,400 B

  hipMemsetAsync(ws, 0, state_f * sizeof(float), stream);

  keys_kernel<<<1, 128, 0, stream>>>(keybuf);
  transpose_w2<<<(25000 + 255) / 256, 256, 0, stream>>>(w2, wT);

  for (int s = 0; s < STEPS; ++s) {
    poisson_t<<<(NIN + 255) / 256, 256, 0, stream>>>(x, keybuf, s, pois);
    conv1_pool1_fused<<<196 * 2, 256, 0, stream>>>(pois, w1, m1, m1s, sp1);
    conv2_fire_t<<<196 * 2, 256, 0, stream>>>(sp1, wT, m2, s2);
    pool_fire_t<<<(1254400 + 255) / 256, 256, 0, stream>>>(s2, m2s, sp2,
                                                           1254400, 14, 0.75f);
    fc0_fire_t4<<<100, 256, 0, stream>>>(sp2, wf0, mf0, Tf0);
  }
  fc1_out_t<<<(BATCH * 10 + 255) / 256, 256, 0, stream>>>(Tf0, wf1, out);
}